// Round 6
// baseline (212.300 us; speedup 1.0000x reference)
//
#include <hip/hip_runtime.h>
#include <hip/hip_bf16.h>

#define NN 50000
#define NE 800000
#define NPW 64   // nodes per wave in the gather kernel

typedef __attribute__((ext_vector_type(4))) float f32x4;
typedef __attribute__((ext_vector_type(8))) __bf16 bf16x8;

__device__ __forceinline__ float wred64(float v) {
    v += __shfl_xor(v, 32, 64);
    v += __shfl_xor(v, 16, 64);
    v += __shfl_xor(v, 8, 64);
    v += __shfl_xor(v, 4, 64);
    v += __shfl_xor(v, 2, 64);
    v += __shfl_xor(v, 1, 64);
    return v;
}

__device__ __forceinline__ float arcosh_f(float z) {
    z = fmaxf(z, 1.0f + 1e-7f);
    return logf(z + sqrtf(z * z - 1.0f));
}

// ---------------------------------------------------------------------------
// prep: pack W^T into MFMA B-fragment-linear order as bf16 hi/lo pair.
// ---------------------------------------------------------------------------
__global__ void prep_kernel(const float* __restrict__ weight, const float* __restrict__ bias,
                            ushort* __restrict__ WfHi, ushort* __restrict__ WfLo,
                            float* __restrict__ biasP) {
    int t8 = blockIdx.x * 256 + threadIdx.x;   // 0..2047 over grid of 8 blocks
    int l = t8 & 63, f = t8 >> 6;
    int t = f & 3, jt = f >> 2;
    int g = l >> 4, r = l & 15;
    int col = jt * 16 + r;
    #pragma unroll
    for (int i = 0; i < 8; ++i) {
        int k = 32 * g + 8 * t + i;
        float v = (col < 127) ? weight[col * 128 + k] : 0.0f;
        __bf16 h = (__bf16)v;
        float lo = v - (float)h;
        __bf16 lb = (__bf16)lo;
        WfHi[t8 * 8 + i] = __builtin_bit_cast(unsigned short, h);
        WfLo[t8 * 8 + i] = __builtin_bit_cast(unsigned short, lb);
    }
    if (t8 < 128) biasP[t8] = (t8 < 127) ? bias[t8] : 0.0f;
}

// ---------------------------------------------------------------------------
// rowptr[r] = first edge with row >= r (rows sorted)
// ---------------------------------------------------------------------------
__global__ void rowptr_kernel(const int* __restrict__ row, int* __restrict__ rowptr) {
    int e = blockIdx.x * 256 + threadIdx.x;
    if (e >= NE) return;
    int r1 = row[e];
    int r0 = (e == 0) ? -1 : row[e - 1];
    for (int r = r0 + 1; r <= r1; ++r) rowptr[r] = e;
    if (e == NE - 1) {
        for (int r = r1 + 1; r <= NN; ++r) rowptr[r] = NE;
    }
}

// ---------------------------------------------------------------------------
// Stage 1 via MFMA (bf16x3 compensated): hh = exp_map_zero([0, W@log0(x)+b])
// Output layout is CHUNK-MAJOR: hhc[chunk][node][i] = component 16*chunk+i,
// with component 127 = head. Chunk c's slice is a contiguous 3.2 MB block.
// ---------------------------------------------------------------------------
__global__ __launch_bounds__(256) void transform_kernel(
        const float* __restrict__ x, const ushort* __restrict__ Wf /* hi|lo 64KB */,
        const float* __restrict__ biasP, float* __restrict__ hhc) {
    __shared__ __align__(16) ushort WF[32768];   // 64 KB: [0,16384) hi, rest lo

    const int tid = threadIdx.x;
    #pragma unroll
    for (int i = 0; i < 16; ++i)
        ((float4*)WF)[i * 256 + tid] = ((const float4*)Wf)[i * 256 + tid];

    const int lane = tid & 63, w = tid >> 6;
    const int g = lane >> 4, r = lane & 15;
    const int nodeA = blockIdx.x * 64 + w * 16 + r;   // A-fragment row

    float xv[32];
    float x0 = 1.0f;
    if (nodeA < NN) {
        const float* xp = x + (long)nodeA * 129;
        x0 = xp[0];
        __builtin_memcpy(xv, xp + 1 + 32 * g, 128);
    } else {
        #pragma unroll
        for (int i = 0; i < 32; ++i) xv[i] = 0.0f;
    }
    // input invariant: x0 = sqrt(1 + sum tail^2)  ->  ssq = x0^2 - 1
    float dist = arcosh_f(x0);
    float sc = dist / sqrtf(fmaxf(x0 * x0 - 1.0f, 1e-6f));

    bf16x8 ah[4], al[4];
    #pragma unroll
    for (int t = 0; t < 4; ++t) {
        #pragma unroll
        for (int i = 0; i < 8; ++i) {
            float v = sc * xv[8 * t + i];
            __bf16 h = (__bf16)v;
            ah[t][i] = h;
            al[t][i] = (__bf16)(v - (float)h);
        }
    }
    __syncthreads();

    f32x4 acc[8];
    #pragma unroll
    for (int jt = 0; jt < 8; ++jt) acc[jt] = (f32x4){0.0f, 0.0f, 0.0f, 0.0f};

    #pragma unroll
    for (int jt = 0; jt < 8; ++jt) {
        #pragma unroll
        for (int t = 0; t < 4; ++t) {
            const int f = jt * 4 + t;
            bf16x8 bh = *(const bf16x8*)&WF[(f * 64 + lane) * 8];
            bf16x8 bl = *(const bf16x8*)&WF[16384 + (f * 64 + lane) * 8];
            acc[jt] = __builtin_amdgcn_mfma_f32_16x16x32_bf16(al[t], bh, acc[jt], 0, 0, 0);
            acc[jt] = __builtin_amdgcn_mfma_f32_16x16x32_bf16(ah[t], bl, acc[jt], 0, 0, 0);
            acc[jt] = __builtin_amdgcn_mfma_f32_16x16x32_bf16(ah[t], bh, acc[jt], 0, 0, 0);
        }
    }

    float bv[8];
    #pragma unroll
    for (int jt = 0; jt < 8; ++jt) bv[jt] = biasP[jt * 16 + r];

    #pragma unroll
    for (int i = 0; i < 4; ++i) {
        float m[8];
        float p = 0.0f;
        #pragma unroll
        for (int jt = 0; jt < 8; ++jt) {
            m[jt] = acc[jt][i] + bv[jt];
            p = fmaf(m[jt], m[jt], p);
        }
        p += __shfl_xor(p, 1, 64);
        p += __shfl_xor(p, 2, 64);
        p += __shfl_xor(p, 4, 64);
        p += __shfl_xor(p, 8, 64);        // p = sum_{j<127} mx_j^2
        float n = sqrtf(fmaxf(p, 1e-6f));
        float rr = sinhf(fminf(n, 50.0f)) / n;
        int node = blockIdx.x * 64 + w * 16 + g * 4 + i;
        if (node < NN) {
            #pragma unroll
            for (int jt = 0; jt < 8; ++jt) {
                int j = jt * 16 + r;
                float v = (j == 127) ? sqrtf(1.0f + rr * rr * p) : rr * m[jt];
                hhc[((long)jt * NN + node) * 16 + r] = v;
            }
        }
    }
}

// ---------------------------------------------------------------------------
// Stage 2a: feature-chunked segment gather-sum, LONG-LIVED waves.
// chunk = blockIdx&7 pins each contiguous 3.2 MB slice hhc[chunk] to one
// XCD's L2. Each wave processes NPW consecutive nodes serially: rowptr
// amortized (lo = prev hi), col/val a contiguous warm stream, gather latency
// overlapped across ~24 resident waves/CU.
// Lane (slot=l>>4, i=l&15): edges lo+slot+4k, component 16*chunk+i.
// ---------------------------------------------------------------------------
__global__ __launch_bounds__(256) void gather_chunk_kernel(
        const float* __restrict__ hhc, const float* __restrict__ val,
        const int* __restrict__ col, const int* __restrict__ rowptr,
        float* __restrict__ s) {
    const int chunk = blockIdx.x & 7;
    const int wave = threadIdx.x >> 6;
    const int lane = threadIdx.x & 63;
    const int i = lane & 15, slot = lane >> 4;
    const int n0 = ((blockIdx.x >> 3) * 4 + wave) * NPW;
    if (n0 >= NN) return;
    const float* hc = hhc + (long)chunk * NN * 16;

    int lo = rowptr[n0];
    for (int k = 0; k < NPW; ++k) {
        const int node = n0 + k;
        if (node >= NN) break;
        const int hi = rowptr[node + 1];
        float sacc = 0.0f;
        int e = lo + slot;
        for (; e + 4 < hi; e += 8) {
            int c0 = col[e], c1 = col[e + 4];
            float v0 = val[e], v1 = val[e + 4];
            sacc = fmaf(v0, hc[(long)c0 * 16 + i], sacc);
            sacc = fmaf(v1, hc[(long)c1 * 16 + i], sacc);
        }
        if (e < hi)
            sacc = fmaf(val[e], hc[(long)col[e] * 16 + i], sacc);

        sacc += __shfl_xor(sacc, 16, 64);
        sacc += __shfl_xor(sacc, 32, 64);
        if (lane < 16) s[(long)node * 128 + chunk * 16 + i] = sacc;
        lo = hi;
    }
}

// ---------------------------------------------------------------------------
// Stage 2b: Lorentz centroid normalize + hyp_act from the summed rows s.
// s layout: standard [node][128] with head at slot 127.
// ---------------------------------------------------------------------------
__global__ __launch_bounds__(256) void finalize_kernel(
        const float* __restrict__ s, float* __restrict__ out) {
    const int lane = threadIdx.x & 63;
    const int node = __builtin_amdgcn_readfirstlane(blockIdx.x * 4 + (threadIdx.x >> 6));

    float2 sv = *(const float2*)&s[(long)node * 128 + 2 * lane];
    float s0 = sv.x, s1 = sv.y;

    const bool isHead = (lane == 63);   // lane 63's second slot is c=127 = head
    float loc = s0 * s0 + (isHead ? -s1 * s1 : s1 * s1);
    float inner = wred64(loc);
    float coef = 1.0f / sqrtf(fmaxf(fabsf(inner), 1e-6f));
    float g0 = coef * s0, g1 = coef * s1;
    float h20 = coef * __shfl(s1, 63, 64);

    float dist = arcosh_f(h20);
    float tl = g0 * g0 + (isHead ? 0.0f : g1 * g1);
    float tsq = wred64(tl);
    float scl = dist / sqrtf(fmaxf(tsq, 1e-6f));
    float u0 = fmaxf(scl * g0, 0.0f);
    float u1 = isHead ? 0.0f : fmaxf(scl * g1, 0.0f);
    float S = wred64(u0 * u0 + u1 * u1);
    float n = sqrtf(fmaxf(S, 1e-6f));
    float r = sinhf(fminf(n, 50.0f)) / n;

    float* op = out + (long)node * 128;
    op[1 + 2 * lane] = r * u0;                       // tail c=2l -> out comp 2l+1
    if (lane < 63) op[2 + 2 * lane] = r * u1;        // tail c=2l+1 -> out comp 2l+2
    else           op[0] = sqrtf(1.0f + r * r * S);  // head
}

// ---------------------------------------------------------------------------
// Fallback stage 2 (single pass, chunk-major hhc) if ws is too small.
// ---------------------------------------------------------------------------
__global__ __launch_bounds__(256) void centroid_act_kernel(
        const float* __restrict__ hhc, const float* __restrict__ val,
        const int* __restrict__ col, const int* __restrict__ rowptr,
        float* __restrict__ out) {
    const int lane = threadIdx.x & 63;
    const int node = __builtin_amdgcn_readfirstlane(blockIdx.x * 4 + (threadIdx.x >> 6));

    const long coff = (long)(lane >> 3) * NN * 16 + ((2 * lane) & 15);
    const int lo = rowptr[node], hi = rowptr[node + 1];
    float s0 = 0.0f, s1 = 0.0f;
    for (int e = lo; e < hi; ++e) {
        int c = col[e];
        float v = val[e];
        float2 a = *(const float2*)&hhc[(long)c * 16 + coff];
        s0 = fmaf(v, a.x, s0); s1 = fmaf(v, a.y, s1);
    }

    const bool isHead = (lane == 63);
    float loc = s0 * s0 + (isHead ? -s1 * s1 : s1 * s1);
    float inner = wred64(loc);
    float coef = 1.0f / sqrtf(fmaxf(fabsf(inner), 1e-6f));
    float g0 = coef * s0, g1 = coef * s1;
    float h20 = coef * __shfl(s1, 63, 64);

    float dist = arcosh_f(h20);
    float tl = g0 * g0 + (isHead ? 0.0f : g1 * g1);
    float tsq = wred64(tl);
    float scl = dist / sqrtf(fmaxf(tsq, 1e-6f));
    float u0 = fmaxf(scl * g0, 0.0f);
    float u1 = isHead ? 0.0f : fmaxf(scl * g1, 0.0f);
    float S = wred64(u0 * u0 + u1 * u1);
    float n = sqrtf(fmaxf(S, 1e-6f));
    float r = sinhf(fminf(n, 50.0f)) / n;

    float* op = out + (long)node * 128;
    op[1 + 2 * lane] = r * u0;
    if (lane < 63) op[2 + 2 * lane] = r * u1;
    else           op[0] = sqrtf(1.0f + r * r * S);
}

extern "C" void kernel_launch(void* const* d_in, const int* in_sizes, int n_in,
                              void* d_out, int out_size, void* d_ws, size_t ws_size,
                              hipStream_t stream) {
    const float* x       = (const float*)d_in[0];
    const float* weight  = (const float*)d_in[1];
    const float* bias    = (const float*)d_in[2];
    const float* adj_val = (const float*)d_in[3];
    const int*   adj_row = (const int*)d_in[4];
    const int*   adj_col = (const int*)d_in[5];
    float* out = (float*)d_out;

    char* ws = (char*)d_ws;
    const size_t HH_B = 25600000;       // 50000*128*4
    const bool chunked = ws_size >= (size_t)51466240;
    size_t base = chunked ? 2 * HH_B : HH_B;

    float*  hhc    = (float*)ws;
    float*  s      = (float*)(ws + HH_B);          // chunked path only
    int*    rowptr = (int*)(ws + base);            // 200,004 B
    ushort* WfHi   = (ushort*)(ws + base + 200192);
    ushort* WfLo   = (ushort*)(ws + base + 232960);
    float*  biasP  = (float*)(ws + base + 265728);

    prep_kernel<<<8, 256, 0, stream>>>(weight, bias, WfHi, WfLo, biasP);
    rowptr_kernel<<<(NE + 255) / 256, 256, 0, stream>>>(adj_row, rowptr);
    transform_kernel<<<(NN + 63) / 64, 256, 0, stream>>>(x, WfHi, biasP, hhc);
    if (chunked) {
        const int blocksPerChunk = (NN + 4 * NPW - 1) / (4 * NPW);   // 196
        gather_chunk_kernel<<<blocksPerChunk * 8, 256, 0, stream>>>(hhc, adj_val, adj_col, rowptr, s);
        finalize_kernel<<<NN / 4, 256, 0, stream>>>(s, out);
    } else {
        centroid_act_kernel<<<NN / 4, 256, 0, stream>>>(hhc, adj_val, adj_col, rowptr, out);
    }
}

// Round 7
// 78.557 us; speedup vs baseline: 2.7025x; 2.7025x over previous
//
#include <hip/hip_runtime.h>
#include <hip/hip_bf16.h>

#define NN 50000
#define NE 800000

typedef __attribute__((ext_vector_type(4))) float f32x4;
typedef __attribute__((ext_vector_type(8))) __bf16 bf16x8;

__device__ __forceinline__ float wred64(float v) {
    v += __shfl_xor(v, 32, 64);
    v += __shfl_xor(v, 16, 64);
    v += __shfl_xor(v, 8, 64);
    v += __shfl_xor(v, 4, 64);
    v += __shfl_xor(v, 2, 64);
    v += __shfl_xor(v, 1, 64);
    return v;
}

__device__ __forceinline__ float arcosh_f(float z) {
    z = fmaxf(z, 1.0f + 1e-7f);
    return logf(z + sqrtf(z * z - 1.0f));
}

// ---------------------------------------------------------------------------
// prep: pack W^T into MFMA B-fragment-linear order as bf16 hi/lo pair.
// ---------------------------------------------------------------------------
__global__ void prep_kernel(const float* __restrict__ weight, const float* __restrict__ bias,
                            ushort* __restrict__ WfHi, ushort* __restrict__ WfLo,
                            float* __restrict__ biasP) {
    int t8 = blockIdx.x * 256 + threadIdx.x;   // 0..2047 over grid of 8 blocks
    int l = t8 & 63, f = t8 >> 6;
    int t = f & 3, jt = f >> 2;
    int g = l >> 4, r = l & 15;
    int col = jt * 16 + r;
    #pragma unroll
    for (int i = 0; i < 8; ++i) {
        int k = 32 * g + 8 * t + i;
        float v = (col < 127) ? weight[col * 128 + k] : 0.0f;
        __bf16 h = (__bf16)v;
        float lo = v - (float)h;
        __bf16 lb = (__bf16)lo;
        WfHi[t8 * 8 + i] = __builtin_bit_cast(unsigned short, h);
        WfLo[t8 * 8 + i] = __builtin_bit_cast(unsigned short, lb);
    }
    if (t8 < 128) biasP[t8] = (t8 < 127) ? bias[t8] : 0.0f;
}

// ---------------------------------------------------------------------------
// rowptr[r] = first edge with row >= r (rows sorted)
// ---------------------------------------------------------------------------
__global__ void rowptr_kernel(const int* __restrict__ row, int* __restrict__ rowptr) {
    int e = blockIdx.x * 256 + threadIdx.x;
    if (e >= NE) return;
    int r1 = row[e];
    int r0 = (e == 0) ? -1 : row[e - 1];
    for (int r = r0 + 1; r <= r1; ++r) rowptr[r] = e;
    if (e == NE - 1) {
        for (int r = r1 + 1; r <= NN; ++r) rowptr[r] = NE;
    }
}

// ---------------------------------------------------------------------------
// Stage 1 via MFMA (bf16x3 compensated): h = exp_map_zero([0, W@log0(x)+b])
// Output: hhb[node][128] bf16 (slot j = tail comp j, j<127; slot 127 = 0)
//         hhead[node]    fp32 head (the precision-critical component)
// ---------------------------------------------------------------------------
__global__ __launch_bounds__(256) void transform_kernel(
        const float* __restrict__ x, const ushort* __restrict__ Wf /* hi|lo 64KB */,
        const float* __restrict__ biasP, ushort* __restrict__ hhb,
        float* __restrict__ hhead) {
    __shared__ __align__(16) ushort WF[32768];   // 64 KB: [0,16384) hi, rest lo

    const int tid = threadIdx.x;
    #pragma unroll
    for (int i = 0; i < 16; ++i)
        ((float4*)WF)[i * 256 + tid] = ((const float4*)Wf)[i * 256 + tid];

    const int lane = tid & 63, w = tid >> 6;
    const int g = lane >> 4, r = lane & 15;
    const int nodeA = blockIdx.x * 64 + w * 16 + r;   // A-fragment row

    float xv[32];
    float x0 = 1.0f;
    if (nodeA < NN) {
        const float* xp = x + (long)nodeA * 129;
        x0 = xp[0];
        __builtin_memcpy(xv, xp + 1 + 32 * g, 128);
    } else {
        #pragma unroll
        for (int i = 0; i < 32; ++i) xv[i] = 0.0f;
    }
    // input invariant: x0 = sqrt(1 + sum tail^2)  ->  ssq = x0^2 - 1
    float dist = arcosh_f(x0);
    float sc = dist / sqrtf(fmaxf(x0 * x0 - 1.0f, 1e-6f));

    bf16x8 ah[4], al[4];
    #pragma unroll
    for (int t = 0; t < 4; ++t) {
        #pragma unroll
        for (int i = 0; i < 8; ++i) {
            float v = sc * xv[8 * t + i];
            __bf16 h = (__bf16)v;
            ah[t][i] = h;
            al[t][i] = (__bf16)(v - (float)h);
        }
    }
    __syncthreads();

    f32x4 acc[8];
    #pragma unroll
    for (int jt = 0; jt < 8; ++jt) acc[jt] = (f32x4){0.0f, 0.0f, 0.0f, 0.0f};

    #pragma unroll
    for (int jt = 0; jt < 8; ++jt) {
        #pragma unroll
        for (int t = 0; t < 4; ++t) {
            const int f = jt * 4 + t;
            bf16x8 bh = *(const bf16x8*)&WF[(f * 64 + lane) * 8];
            bf16x8 bl = *(const bf16x8*)&WF[16384 + (f * 64 + lane) * 8];
            acc[jt] = __builtin_amdgcn_mfma_f32_16x16x32_bf16(al[t], bh, acc[jt], 0, 0, 0);
            acc[jt] = __builtin_amdgcn_mfma_f32_16x16x32_bf16(ah[t], bl, acc[jt], 0, 0, 0);
            acc[jt] = __builtin_amdgcn_mfma_f32_16x16x32_bf16(ah[t], bh, acc[jt], 0, 0, 0);
        }
    }

    float bv[8];
    #pragma unroll
    for (int jt = 0; jt < 8; ++jt) bv[jt] = biasP[jt * 16 + r];

    #pragma unroll
    for (int i = 0; i < 4; ++i) {
        float m[8];
        float p = 0.0f;
        #pragma unroll
        for (int jt = 0; jt < 8; ++jt) {
            m[jt] = acc[jt][i] + bv[jt];
            p = fmaf(m[jt], m[jt], p);
        }
        p += __shfl_xor(p, 1, 64);
        p += __shfl_xor(p, 2, 64);
        p += __shfl_xor(p, 4, 64);
        p += __shfl_xor(p, 8, 64);        // p = sum_{j<127} mx_j^2
        float n = sqrtf(fmaxf(p, 1e-6f));
        float rr = sinhf(fminf(n, 50.0f)) / n;
        int node = blockIdx.x * 64 + w * 16 + g * 4 + i;
        if (node < NN) {
            #pragma unroll
            for (int jt = 0; jt < 8; ++jt) {
                int j = jt * 16 + r;
                float vv = rr * m[jt];
                ushort us = (j == 127) ? (ushort)0
                          : __builtin_bit_cast(unsigned short, (__bf16)vv);
                hhb[node * 128 + j] = us;
            }
            if (r == 15) hhead[node] = sqrtf(1.0f + rr * rr * p);
        }
    }
}

// ---------------------------------------------------------------------------
// Stage 2+3 fused: segment gather-sum (bf16 tail + fp32 head), Lorentz
// centroid normalize, hyp_act. One wave per node; lane holds tail comps
// 2l, 2l+1 (slot 127 is a zero pad). s0 is computed wave-uniform from the
// fp32 head array (precision-critical: inner cancels, arcosh amplifies).
// Edge indices are wave-uniform -> col/val/head loads take the scalar path.
// ---------------------------------------------------------------------------
__global__ __launch_bounds__(256) void centroid_act_kernel(
        const ushort* __restrict__ hhb, const float* __restrict__ hhead,
        const float* __restrict__ val, const int* __restrict__ col,
        const int* __restrict__ rowptr, float* __restrict__ out) {
    const int lane = threadIdx.x & 63;
    const int node = __builtin_amdgcn_readfirstlane(blockIdx.x * 4 + (threadIdx.x >> 6));
    const int lo = __builtin_amdgcn_readfirstlane(rowptr[node]);
    const int hi = __builtin_amdgcn_readfirstlane(rowptr[node + 1]);

    float s0 = 0.0f, sf0 = 0.0f, sf1 = 0.0f;
    int e = lo;
    for (; e + 8 <= hi; e += 8) {
        int c[8]; float v[8];
        #pragma unroll
        for (int k = 0; k < 8; ++k) { c[k] = col[e + k]; v[k] = val[e + k]; }
        uint u[8]; float hd[8];
        #pragma unroll
        for (int k = 0; k < 8; ++k) {
            u[k]  = *(const uint*)&hhb[((long)c[k] << 7) + 2 * lane];
            hd[k] = hhead[c[k]];
        }
        #pragma unroll
        for (int k = 0; k < 8; ++k) {
            float f0 = __builtin_bit_cast(float, u[k] << 16);
            float f1 = __builtin_bit_cast(float, u[k] & 0xffff0000u);
            sf0 = fmaf(v[k], f0, sf0);
            sf1 = fmaf(v[k], f1, sf1);
            s0  = fmaf(v[k], hd[k], s0);
        }
    }
    for (; e < hi; ++e) {
        int c = col[e]; float v = val[e];
        uint u = *(const uint*)&hhb[((long)c << 7) + 2 * lane];
        sf0 = fmaf(v, __builtin_bit_cast(float, u << 16), sf0);
        sf1 = fmaf(v, __builtin_bit_cast(float, u & 0xffff0000u), sf1);
        s0  = fmaf(v, hhead[c], s0);
    }

    // Lorentz inner = sum_tail s_f^2 - s0^2 (slot 127 pad contributes 0)
    float tsum = wred64(sf0 * sf0 + sf1 * sf1);
    float inner = tsum - s0 * s0;
    float coef = 1.0f / sqrtf(fmaxf(fabsf(inner), 1e-6f));
    float h20 = coef * s0;                       // wave-uniform

    // hyp_act = exp_map_zero(relu(log_map_zero(h2)))
    float dist = arcosh_f(h20);
    float tsq = coef * coef * tsum;              // ||h2 tail||^2, no reduce needed
    float scl = dist / sqrtf(fmaxf(tsq, 1e-6f));
    float u0 = fmaxf(scl * coef * sf0, 0.0f);
    float u1 = fmaxf(scl * coef * sf1, 0.0f);    // lane63: sf1==0 -> u1==0
    float S = wred64(u0 * u0 + u1 * u1);
    float n = sqrtf(fmaxf(S, 1e-6f));
    float r = sinhf(fminf(n, 50.0f)) / n;

    float* op = out + (long)node * 128;
    op[1 + 2 * lane] = r * u0;                       // tail c=2l -> out comp 2l+1
    if (lane < 63) op[2 + 2 * lane] = r * u1;        // tail c=2l+1 -> out comp 2l+2
    else           op[0] = sqrtf(1.0f + r * r * S);  // head
}

extern "C" void kernel_launch(void* const* d_in, const int* in_sizes, int n_in,
                              void* d_out, int out_size, void* d_ws, size_t ws_size,
                              hipStream_t stream) {
    const float* x       = (const float*)d_in[0];
    const float* weight  = (const float*)d_in[1];
    const float* bias    = (const float*)d_in[2];
    const float* adj_val = (const float*)d_in[3];
    const int*   adj_row = (const int*)d_in[4];
    const int*   adj_col = (const int*)d_in[5];
    float* out = (float*)d_out;

    char* ws = (char*)d_ws;
    ushort* hhb    = (ushort*)ws;                   // 12,800,000 B
    float*  hhead  = (float*)(ws + 12800000);       // 200,000 B
    int*    rowptr = (int*)(ws + 13000000);         // 200,004 B
    ushort* WfHi   = (ushort*)(ws + 13200192);      // 32,768 B
    ushort* WfLo   = (ushort*)(ws + 13232960);      // 32,768 B
    float*  biasP  = (float*)(ws + 13265728);       // 512 B

    prep_kernel<<<8, 256, 0, stream>>>(weight, bias, WfHi, WfLo, biasP);
    rowptr_kernel<<<(NE + 255) / 256, 256, 0, stream>>>(adj_row, rowptr);
    transform_kernel<<<(NN + 63) / 64, 256, 0, stream>>>(x, WfHi, biasP, hhb, hhead);
    centroid_act_kernel<<<NN / 4, 256, 0, stream>>>(hhb, hhead, adj_val, adj_col, rowptr, out);
}

// Round 8
// 76.212 us; speedup vs baseline: 2.7857x; 1.0308x over previous
//
#include <hip/hip_runtime.h>
#include <hip/hip_bf16.h>

#define NN 50000
#define NE 800000

typedef __attribute__((ext_vector_type(4))) float f32x4;
typedef __attribute__((ext_vector_type(8))) __bf16 bf16x8;

__device__ __forceinline__ float wred64(float v) {
    v += __shfl_xor(v, 32, 64);
    v += __shfl_xor(v, 16, 64);
    v += __shfl_xor(v, 8, 64);
    v += __shfl_xor(v, 4, 64);
    v += __shfl_xor(v, 2, 64);
    v += __shfl_xor(v, 1, 64);
    return v;
}

__device__ __forceinline__ float arcosh_f(float z) {
    z = fmaxf(z, 1.0f + 1e-7f);
    return logf(z + sqrtf(z * z - 1.0f));
}

// ---------------------------------------------------------------------------
// prep: pack W^T into MFMA B-fragment-linear order as bf16 hi/lo pair.
// ---------------------------------------------------------------------------
__global__ void prep_kernel(const float* __restrict__ weight, const float* __restrict__ bias,
                            ushort* __restrict__ WfHi, ushort* __restrict__ WfLo,
                            float* __restrict__ biasP) {
    int t8 = blockIdx.x * 256 + threadIdx.x;   // 0..2047 over grid of 8 blocks
    int l = t8 & 63, f = t8 >> 6;
    int t = f & 3, jt = f >> 2;
    int g = l >> 4, r = l & 15;
    int col = jt * 16 + r;
    #pragma unroll
    for (int i = 0; i < 8; ++i) {
        int k = 32 * g + 8 * t + i;
        float v = (col < 127) ? weight[col * 128 + k] : 0.0f;
        __bf16 h = (__bf16)v;
        float lo = v - (float)h;
        __bf16 lb = (__bf16)lo;
        WfHi[t8 * 8 + i] = __builtin_bit_cast(unsigned short, h);
        WfLo[t8 * 8 + i] = __builtin_bit_cast(unsigned short, lb);
    }
    if (t8 < 128) biasP[t8] = (t8 < 127) ? bias[t8] : 0.0f;
}

// ---------------------------------------------------------------------------
// rowptr[r] = first edge with row >= r (rows sorted)
// ---------------------------------------------------------------------------
__global__ void rowptr_kernel(const int* __restrict__ row, int* __restrict__ rowptr) {
    int e = blockIdx.x * 256 + threadIdx.x;
    if (e >= NE) return;
    int r1 = row[e];
    int r0 = (e == 0) ? -1 : row[e - 1];
    for (int r = r0 + 1; r <= r1; ++r) rowptr[r] = e;
    if (e == NE - 1) {
        for (int r = r1 + 1; r <= NN; ++r) rowptr[r] = NE;
    }
}

// ---------------------------------------------------------------------------
// Stage 1 via MFMA (bf16x3 compensated): h = exp_map_zero([0, W@log0(x)+b])
// Output: hhb[node][128] bf16 (slot j = tail comp j, j<127; slot 127 = 0)
//         hhead[node]    fp32 head (the precision-critical component)
// ---------------------------------------------------------------------------
__global__ __launch_bounds__(256) void transform_kernel(
        const float* __restrict__ x, const ushort* __restrict__ Wf /* hi|lo 64KB */,
        const float* __restrict__ biasP, ushort* __restrict__ hhb,
        float* __restrict__ hhead) {
    __shared__ __align__(16) ushort WF[32768];   // 64 KB: [0,16384) hi, rest lo

    const int tid = threadIdx.x;
    #pragma unroll
    for (int i = 0; i < 16; ++i)
        ((float4*)WF)[i * 256 + tid] = ((const float4*)Wf)[i * 256 + tid];

    const int lane = tid & 63, w = tid >> 6;
    const int g = lane >> 4, r = lane & 15;
    const int nodeA = blockIdx.x * 64 + w * 16 + r;   // A-fragment row

    float xv[32];
    float x0 = 1.0f;
    if (nodeA < NN) {
        const float* xp = x + (long)nodeA * 129;
        x0 = xp[0];
        __builtin_memcpy(xv, xp + 1 + 32 * g, 128);
    } else {
        #pragma unroll
        for (int i = 0; i < 32; ++i) xv[i] = 0.0f;
    }
    // input invariant: x0 = sqrt(1 + sum tail^2)  ->  ssq = x0^2 - 1
    float dist = arcosh_f(x0);
    float sc = dist / sqrtf(fmaxf(x0 * x0 - 1.0f, 1e-6f));

    bf16x8 ah[4], al[4];
    #pragma unroll
    for (int t = 0; t < 4; ++t) {
        #pragma unroll
        for (int i = 0; i < 8; ++i) {
            float v = sc * xv[8 * t + i];
            __bf16 h = (__bf16)v;
            ah[t][i] = h;
            al[t][i] = (__bf16)(v - (float)h);
        }
    }
    __syncthreads();

    f32x4 acc[8];
    #pragma unroll
    for (int jt = 0; jt < 8; ++jt) acc[jt] = (f32x4){0.0f, 0.0f, 0.0f, 0.0f};

    #pragma unroll
    for (int jt = 0; jt < 8; ++jt) {
        #pragma unroll
        for (int t = 0; t < 4; ++t) {
            const int f = jt * 4 + t;
            bf16x8 bh = *(const bf16x8*)&WF[(f * 64 + lane) * 8];
            bf16x8 bl = *(const bf16x8*)&WF[16384 + (f * 64 + lane) * 8];
            acc[jt] = __builtin_amdgcn_mfma_f32_16x16x32_bf16(al[t], bh, acc[jt], 0, 0, 0);
            acc[jt] = __builtin_amdgcn_mfma_f32_16x16x32_bf16(ah[t], bl, acc[jt], 0, 0, 0);
            acc[jt] = __builtin_amdgcn_mfma_f32_16x16x32_bf16(ah[t], bh, acc[jt], 0, 0, 0);
        }
    }

    float bv[8];
    #pragma unroll
    for (int jt = 0; jt < 8; ++jt) bv[jt] = biasP[jt * 16 + r];

    #pragma unroll
    for (int i = 0; i < 4; ++i) {
        float m[8];
        float p = 0.0f;
        #pragma unroll
        for (int jt = 0; jt < 8; ++jt) {
            m[jt] = acc[jt][i] + bv[jt];
            p = fmaf(m[jt], m[jt], p);
        }
        p += __shfl_xor(p, 1, 64);
        p += __shfl_xor(p, 2, 64);
        p += __shfl_xor(p, 4, 64);
        p += __shfl_xor(p, 8, 64);        // p = sum_{j<127} mx_j^2
        float n = sqrtf(fmaxf(p, 1e-6f));
        float rr = sinhf(fminf(n, 50.0f)) / n;
        int node = blockIdx.x * 64 + w * 16 + g * 4 + i;
        if (node < NN) {
            #pragma unroll
            for (int jt = 0; jt < 8; ++jt) {
                int j = jt * 16 + r;
                float vv = rr * m[jt];
                ushort us = (j == 127) ? (ushort)0
                          : __builtin_bit_cast(unsigned short, (__bf16)vv);
                hhb[node * 128 + j] = us;
            }
            if (r == 15) hhead[node] = sqrtf(1.0f + rr * rr * p);
        }
    }
}

// ---------------------------------------------------------------------------
// Stage 2+3 fused: segment gather-sum (bf16 tail rows + fp32 head), Lorentz
// centroid normalize, hyp_act. One wave per node; lane holds tail comps
// 2l, 2l+1 (slot 127 is a zero pad).
// Heads are gathered on the VECTOR pipe by lane-spreading: lane l handles
// edge e+(l&3); each edge replicated on 16 lanes, s0 = wred64/16 (exact).
// This avoids the scalar s_load chain that serialized round 7.
// ---------------------------------------------------------------------------
__global__ __launch_bounds__(256) void centroid_act_kernel(
        const ushort* __restrict__ hhb, const float* __restrict__ hhead,
        const float* __restrict__ val, const int* __restrict__ col,
        const int* __restrict__ rowptr, float* __restrict__ out) {
    const int lane = threadIdx.x & 63;
    const int node = __builtin_amdgcn_readfirstlane(blockIdx.x * 4 + (threadIdx.x >> 6));
    const int lo = rowptr[node], hi = rowptr[node + 1];
    const int ls = lane & 3;

    float s0p = 0.0f, sf0 = 0.0f, sf1 = 0.0f;
    int e = lo;
    for (; e + 4 <= hi; e += 4) {
        // head path: per-lane divergent addresses -> vector gather
        int cs = col[e + ls];
        float vs = val[e + ls];
        s0p = fmaf(vs, hhead[cs], s0p);
        // tail path: whole-wave 256B row gathers, 4 in flight
        int c0 = col[e], c1 = col[e + 1], c2 = col[e + 2], c3 = col[e + 3];
        float v0 = val[e], v1 = val[e + 1], v2 = val[e + 2], v3 = val[e + 3];
        uint a = *(const uint*)&hhb[((long)c0 << 7) + 2 * lane];
        uint b = *(const uint*)&hhb[((long)c1 << 7) + 2 * lane];
        uint c = *(const uint*)&hhb[((long)c2 << 7) + 2 * lane];
        uint d = *(const uint*)&hhb[((long)c3 << 7) + 2 * lane];
        sf0 = fmaf(v0, __builtin_bit_cast(float, a << 16), sf0);
        sf1 = fmaf(v0, __builtin_bit_cast(float, a & 0xffff0000u), sf1);
        sf0 = fmaf(v1, __builtin_bit_cast(float, b << 16), sf0);
        sf1 = fmaf(v1, __builtin_bit_cast(float, b & 0xffff0000u), sf1);
        sf0 = fmaf(v2, __builtin_bit_cast(float, c << 16), sf0);
        sf1 = fmaf(v2, __builtin_bit_cast(float, c & 0xffff0000u), sf1);
        sf0 = fmaf(v3, __builtin_bit_cast(float, d << 16), sf0);
        sf1 = fmaf(v3, __builtin_bit_cast(float, d & 0xffff0000u), sf1);
    }
    const int rem = hi - e;
    if (rem > 0) {
        if (ls < rem) {
            int cs = col[e + ls];
            float vs = val[e + ls];
            s0p = fmaf(vs, hhead[cs], s0p);
        }
        for (int k = 0; k < rem; ++k) {
            int c = col[e + k];
            float v = val[e + k];
            uint u = *(const uint*)&hhb[((long)c << 7) + 2 * lane];
            sf0 = fmaf(v, __builtin_bit_cast(float, u << 16), sf0);
            sf1 = fmaf(v, __builtin_bit_cast(float, u & 0xffff0000u), sf1);
        }
    }

    float s0 = wred64(s0p) * 0.0625f;            // each edge counted by 16 lanes

    // Lorentz inner = sum_tail s_f^2 - s0^2 (slot 127 pad contributes 0)
    float tsum = wred64(sf0 * sf0 + sf1 * sf1);
    float inner = tsum - s0 * s0;
    float coef = 1.0f / sqrtf(fmaxf(fabsf(inner), 1e-6f));
    float h20 = coef * s0;                       // wave-uniform

    // hyp_act = exp_map_zero(relu(log_map_zero(h2)))
    float dist = arcosh_f(h20);
    float tsq = coef * coef * tsum;              // ||h2 tail||^2, no reduce needed
    float scl = dist / sqrtf(fmaxf(tsq, 1e-6f));
    float u0 = fmaxf(scl * coef * sf0, 0.0f);
    float u1 = fmaxf(scl * coef * sf1, 0.0f);    // lane63: sf1==0 -> u1==0
    float S = wred64(u0 * u0 + u1 * u1);
    float n = sqrtf(fmaxf(S, 1e-6f));
    float r = sinhf(fminf(n, 50.0f)) / n;

    float* op = out + (long)node * 128;
    op[1 + 2 * lane] = r * u0;                       // tail c=2l -> out comp 2l+1
    if (lane < 63) op[2 + 2 * lane] = r * u1;        // tail c=2l+1 -> out comp 2l+2
    else           op[0] = sqrtf(1.0f + r * r * S);  // head
}

extern "C" void kernel_launch(void* const* d_in, const int* in_sizes, int n_in,
                              void* d_out, int out_size, void* d_ws, size_t ws_size,
                              hipStream_t stream) {
    const float* x       = (const float*)d_in[0];
    const float* weight  = (const float*)d_in[1];
    const float* bias    = (const float*)d_in[2];
    const float* adj_val = (const float*)d_in[3];
    const int*   adj_row = (const int*)d_in[4];
    const int*   adj_col = (const int*)d_in[5];
    float* out = (float*)d_out;

    char* ws = (char*)d_ws;
    ushort* hhb    = (ushort*)ws;                   // 12,800,000 B
    float*  hhead  = (float*)(ws + 12800000);       // 200,000 B
    int*    rowptr = (int*)(ws + 13000000);         // 200,004 B
    ushort* WfHi   = (ushort*)(ws + 13200192);      // 32,768 B
    ushort* WfLo   = (ushort*)(ws + 13232960);      // 32,768 B
    float*  biasP  = (float*)(ws + 13265728);       // 512 B

    prep_kernel<<<8, 256, 0, stream>>>(weight, bias, WfHi, WfLo, biasP);
    rowptr_kernel<<<(NE + 255) / 256, 256, 0, stream>>>(adj_row, rowptr);
    transform_kernel<<<(NN + 63) / 64, 256, 0, stream>>>(x, WfHi, biasP, hhb, hhead);
    centroid_act_kernel<<<NN / 4, 256, 0, stream>>>(hhb, hhead, adj_val, adj_col, rowptr, out);
}